// Round 5
// baseline (302.293 us; speedup 1.0000x reference)
//
#include <hip/hip_runtime.h>
#include <math.h>

#define BATCH 32
#define DIM   4096
#define CLEN  4096
#define HD    128
#define NKV   8
#define NHEAD 32
#define QKVN  6144          // (32 + 2*8) * 128
#define KVSTR (NKV * HD)    // 1024 floats between consecutive t rows
#define GN    64            // N per gemm block
#define KSEG  128           // K floats per stage
#define KSTG  4             // stages per block
#define KTOT  512           // KSEG*KSTG
#define NSEG  8             // 4096 / 512
#define NCHB  16            // chunks per b (one block each)
#define TC    256           // rows per block-chunk
#define NSLOT 16            // one slot per chunk
#define MNEG  -1.0e30f
#define SMASK -3.0e38f

// ---------------- helpers ----------------
__device__ __forceinline__ void gload_lds16(const float* g, float* l) {
  __builtin_amdgcn_global_load_lds(
      (const __attribute__((address_space(1))) void*)g,
      (__attribute__((address_space(3))) void*)l, 16, 0, 0);
}

template <int CTRL>
__device__ __forceinline__ float dpp_add(float x) {
  int y = __builtin_amdgcn_update_dpp(0, __float_as_int(x), CTRL, 0xF, 0xF, true);
  return x + __int_as_float(y);
}

// sum across the 32 lanes of each half-wave
__device__ __forceinline__ float half_reduce(float s) {
  s = dpp_add<0xB1>(s);    // quad_perm xor1
  s = dpp_add<0x4E>(s);    // quad_perm xor2
  s = dpp_add<0x124>(s);   // row_ror:4
  s = dpp_add<0x128>(s);   // row_ror:8
  s += __int_as_float(__builtin_amdgcn_ds_swizzle(__float_as_int(s), 0x401F)); // xor16
  return s;
}

// ---------------- skinny GEMM partial: part[seg][b][n] = sum_{k in seg} X[b][k]*W[n][k]
// DMA staging (global_load_lds w=16) into linear [row][k] tiles, double-buffered.
// Bank conflicts avoided by pre-swizzling the GLOBAL source: quad kq of row r is
// stored at quad (kq ^ s(r)); s_X(r)=(r>>2)&7, s_W(r)=(r>>1)&7. Compute reads use
// the same XOR (per-thread constant: bsel / tsel&7) -> 8 distinct bank-quads.
__global__ __launch_bounds__(256)
void gemm_partial(const float* __restrict__ X, const float* __restrict__ W,
                  float* __restrict__ part, const int N) {
  __shared__ float xs[2][BATCH * KSEG];   // 2 x 16 KB
  __shared__ float wl[2][GN * KSEG];      // 2 x 32 KB
  const int tid  = threadIdx.x;
  const int wid  = tid >> 6;
  const int kqst = tid & 31;          // staging quad index
  const int rsub = tid >> 5;          // staging row parity (0..7)
  const int n0   = blockIdx.x * GN;
  const int k00  = blockIdx.y * KTOT;
  const int bsel = tid & 7;           // compute: b-group, also X swizzle
  const int tsel = tid >> 3;          // compute: 0..31, W swizzle = tsel&7
  const int bq4  = bsel << 2;
  const int nq   = tsel << 1;

  float a00=0,a01=0, a10=0,a11=0, a20=0,a21=0, a30=0,a31=0;

  auto stage = [&](int buf, int k0) {
    // X: 4 wave-rounds, 2 rows each (rows 0..31)
#pragma unroll
    for (int i = 0; i < 4; ++i) {
      const int row = i * 8 + rsub;
      const int sx  = (row >> 2) & 7;
      gload_lds16(X + (size_t)row * DIM + k0 + 4 * (kqst ^ sx),
                  &xs[buf][(i * 8 + wid * 2) * KSEG]);
    }
    // W: 8 wave-rounds, 2 rows each (rows 0..63)
#pragma unroll
    for (int j = 0; j < 8; ++j) {
      const int row = j * 8 + rsub;
      const int sw  = (row >> 1) & 7;
      gload_lds16(W + (size_t)(n0 + row) * DIM + k0 + 4 * (kqst ^ sw),
                  &wl[buf][(j * 8 + wid * 2) * KSEG]);
    }
  };

  stage(0, k00);
  __syncthreads();                    // vmcnt(0) drained by barrier
  int buf = 0;
  for (int kk = 0; kk < KSTG; ++kk) {
    if (kk + 1 < KSTG) stage(buf ^ 1, k00 + (kk + 1) * KSEG);
    const float* xb = &xs[buf][0];
    const float* wb = &wl[buf][0];
#pragma unroll 8
    for (int kq = 0; kq < 32; ++kq) {
      const int xo = 4 * (kq ^ bsel);
      const int wo = 4 * (kq ^ (tsel & 7));
      const float4 x0 = *(const float4*)(xb + (bq4 + 0) * KSEG + xo);
      const float4 x1 = *(const float4*)(xb + (bq4 + 1) * KSEG + xo);
      const float4 x2 = *(const float4*)(xb + (bq4 + 2) * KSEG + xo);
      const float4 x3 = *(const float4*)(xb + (bq4 + 3) * KSEG + xo);
      const float4 w0 = *(const float4*)(wb + (nq + 0) * KSEG + wo);
      const float4 w1 = *(const float4*)(wb + (nq + 1) * KSEG + wo);
      a00 = fmaf(x0.x,w0.x,a00); a00 = fmaf(x0.y,w0.y,a00); a00 = fmaf(x0.z,w0.z,a00); a00 = fmaf(x0.w,w0.w,a00);
      a01 = fmaf(x0.x,w1.x,a01); a01 = fmaf(x0.y,w1.y,a01); a01 = fmaf(x0.z,w1.z,a01); a01 = fmaf(x0.w,w1.w,a01);
      a10 = fmaf(x1.x,w0.x,a10); a10 = fmaf(x1.y,w0.y,a10); a10 = fmaf(x1.z,w0.z,a10); a10 = fmaf(x1.w,w0.w,a10);
      a11 = fmaf(x1.x,w1.x,a11); a11 = fmaf(x1.y,w1.y,a11); a11 = fmaf(x1.z,w1.z,a11); a11 = fmaf(x1.w,w1.w,a11);
      a20 = fmaf(x2.x,w0.x,a20); a20 = fmaf(x2.y,w0.y,a20); a20 = fmaf(x2.z,w0.z,a20); a20 = fmaf(x2.w,w0.w,a20);
      a21 = fmaf(x2.x,w1.x,a21); a21 = fmaf(x2.y,w1.y,a21); a21 = fmaf(x2.z,w1.z,a21); a21 = fmaf(x2.w,w1.w,a21);
      a30 = fmaf(x3.x,w0.x,a30); a30 = fmaf(x3.y,w0.y,a30); a30 = fmaf(x3.z,w0.z,a30); a30 = fmaf(x3.w,w0.w,a30);
      a31 = fmaf(x3.x,w1.x,a31); a31 = fmaf(x3.y,w1.y,a31); a31 = fmaf(x3.z,w1.z,a31); a31 = fmaf(x3.w,w1.w,a31);
    }
    __syncthreads();                  // next-stage DMA landed + LDS safe to reuse
    buf ^= 1;
  }
  float* base = part + ((size_t)blockIdx.y * BATCH + bq4) * N + n0 + nq;
  *(float2*)(base)         = make_float2(a00, a01);
  *(float2*)(base + N)     = make_float2(a10, a11);
  *(float2*)(base + 2 * N) = make_float2(a20, a21);
  *(float2*)(base + 3 * N) = make_float2(a30, a31);
}

// ---------------- qkv combine + RoPE ----------------
__global__ __launch_bounds__(256)
void qkv_combine(const float* __restrict__ part, const int* __restrict__ ctxp,
                 float* __restrict__ qw, float* __restrict__ kn, float* __restrict__ vn) {
  const int idx = blockIdx.x * 256 + threadIdx.x;  // pair index: 32*3072
  const int b  = idx / (QKVN / 2);
  const int c  = idx % (QKVN / 2);
  const int n0 = c * 2;
  float v0 = 0.f, v1 = 0.f;
#pragma unroll
  for (int s = 0; s < NSEG; ++s) {
    const float2 pv = *(const float2*)(part + ((size_t)s * BATCH + b) * QKVN + n0);
    v0 += pv.x; v1 += pv.y;
  }
  const float pos = (float)ctxp[0];
  const float L2T_OVER_64 = 0.20762050593045952f;  // log2(10000)/64
  if (n0 < DIM) {
    const int i = (n0 & 127) >> 1;
    const float fr = exp2f(-(float)i * L2T_OVER_64);
    float sn, cs; sincosf(pos * fr, &sn, &cs);
    qw[(size_t)b * DIM + n0]     = v0 * cs - v1 * sn;
    qw[(size_t)b * DIM + n0 + 1] = v0 * sn + v1 * cs;
  } else if (n0 < DIM + NKV * HD) {
    const int nk = n0 - DIM;
    const int i = (nk & 127) >> 1;
    const float fr = exp2f(-(float)i * L2T_OVER_64);
    float sn, cs; sincosf(pos * fr, &sn, &cs);
    kn[(size_t)b * (NKV * HD) + nk]     = v0 * cs - v1 * sn;
    kn[(size_t)b * (NKV * HD) + nk + 1] = v0 * sn + v1 * cs;
  } else {
    const int nv = n0 - DIM - NKV * HD;
    vn[(size_t)b * (NKV * HD) + nv]     = v0;
    vn[(size_t)b * (NKV * HD) + nv + 1] = v1;
  }
}

// ---------------- flash-decode: dense-row streaming, block owns (b, chunk) ----------------
__device__ __forceinline__ void load4(float4 kb[4], float4 vb[4],
    const float* __restrict__ kbase, const float* __restrict__ vbase,
    const float* __restrict__ knr, const float* __restrict__ vnr,
    const int t0, const int ctx, const bool edge) {
#pragma unroll
  for (int u = 0; u < 4; ++u) {
    const int row = t0 + u;
    const float* kp = kbase + (size_t)row * KVSTR;
    const float* vp = vbase + (size_t)row * KVSTR;
    if (edge) {                       // wave-uniform branch
      if (row == ctx) { kp = knr; vp = vnr; }
    }
    kb[u] = *(const float4*)kp;
    vb[u] = *(const float4*)vp;
  }
}

__device__ __forceinline__ void compute4(const float4 kb[4], const float4 vb[4],
    const float4 q[4], const int t0, const int ctx, const bool edge,
    float m[4], float l[4], float4 acc[4]) {
#pragma unroll
  for (int u = 0; u < 4; ++u) {
    float s[4];
#pragma unroll
    for (int hh = 0; hh < 4; ++hh) {
      float d = fmaf(kb[u].x, q[hh].x, kb[u].y * q[hh].y);
      d = fmaf(kb[u].z, q[hh].z, d);
      d = fmaf(kb[u].w, q[hh].w, d);
      s[hh] = half_reduce(d);
    }
    if (edge) {                       // wave-uniform branch (row uniform across wave)
      if (t0 + u > ctx) { s[0] = SMASK; s[1] = SMASK; s[2] = SMASK; s[3] = SMASK; }
    }
    if ((s[0] > m[0]) | (s[1] > m[1]) | (s[2] > m[2]) | (s[3] > m[3])) {
#pragma unroll
      for (int hh = 0; hh < 4; ++hh) {
        const float mn = fmaxf(m[hh], s[hh]);
        const float rs = __expf(m[hh] - mn);
        l[hh] *= rs;
        acc[hh].x *= rs; acc[hh].y *= rs; acc[hh].z *= rs; acc[hh].w *= rs;
        m[hh] = mn;
      }
    }
#pragma unroll
    for (int hh = 0; hh < 4; ++hh) {
      const float p = __expf(s[hh] - m[hh]);
      l[hh] += p;
      acc[hh].x = fmaf(p, vb[u].x, acc[hh].x);
      acc[hh].y = fmaf(p, vb[u].y, acc[hh].y);
      acc[hh].z = fmaf(p, vb[u].z, acc[hh].z);
      acc[hh].w = fmaf(p, vb[u].w, acc[hh].w);
    }
  }
}

__global__ __launch_bounds__(256)
void attn_fd(const float* __restrict__ qw, const float* __restrict__ knew,
             const float* __restrict__ vnew, const float* __restrict__ ck,
             const float* __restrict__ cv, const int* __restrict__ ctxp,
             float* __restrict__ opart, float* __restrict__ mlp) {
  const int b    = blockIdx.x >> 4;
  const int cidx = blockIdx.x & (NCHB - 1);
  const int wid  = threadIdx.x >> 6;
  const int lane = threadIdx.x & 63;
  const int half = lane >> 5;
  const int g    = wid * 2 + half;
  const int d4   = (lane & 31) << 2;
  const int ctx  = ctxp[0];
  const int c0   = cidx * TC;

  const float sc = 0.08838834764831845f;   // 1/sqrt(128)
  float4 q[4];
#pragma unroll
  for (int hh = 0; hh < 4; ++hh) {
    q[hh] = *(const float4*)(qw + ((size_t)b * NHEAD + g * 4 + hh) * HD + d4);
    q[hh].x *= sc; q[hh].y *= sc; q[hh].z *= sc; q[hh].w *= sc;
  }
  const float* kbase = ck + ((size_t)b * CLEN) * KVSTR + g * HD + d4;
  const float* vbase = cv + ((size_t)b * CLEN) * KVSTR + g * HD + d4;
  const float* knr   = knew + ((size_t)b * NKV + g) * HD + d4;
  const float* vnr   = vnew + ((size_t)b * NKV + g) * HD + d4;

  float m[4] = {MNEG, MNEG, MNEG, MNEG};
  float l[4] = {0.f, 0.f, 0.f, 0.f};
  float4 acc[4] = {};

  float4 kA[4], vA[4], kB[4], vB[4];
  load4(kA, vA, kbase, vbase, knr, vnr, c0, ctx, c0 + 4 > ctx);
  for (int it = 0; it < TC / 8; ++it) {
    const int t0 = c0 + it * 8;
    load4(kB, vB, kbase, vbase, knr, vnr, t0 + 4, ctx, t0 + 8 > ctx);
    compute4(kA, vA, q, t0, ctx, t0 + 4 > ctx, m, l, acc);
    if (it + 1 < TC / 8)
      load4(kA, vA, kbase, vbase, knr, vnr, t0 + 8, ctx, t0 + 12 > ctx);
    compute4(kB, vB, q, t0 + 4, ctx, t0 + 8 > ctx, m, l, acc);
  }

#pragma unroll
  for (int hh = 0; hh < 4; ++hh) {
    const int hid = b * NHEAD + g * 4 + hh;
    const size_t slot = (size_t)hid * NSLOT + cidx;
    *(float4*)(opart + slot * HD + d4) = acc[hh];
    if ((lane & 31) == 0) { mlp[slot * 2] = m[hh]; mlp[slot * 2 + 1] = l[hh]; }
  }
}

// ---------------- flash combine ----------------
__global__ __launch_bounds__(128)
void attn_combine(const float* __restrict__ opart, const float* __restrict__ mlp,
                  float* __restrict__ ow) {
  const int p = blockIdx.x;      // 0..1023 = b*32 + g*4 + h
  const int d = threadIdx.x;     // 0..127
  float M = MNEG;
#pragma unroll
  for (int c = 0; c < NSLOT; ++c) M = fmaxf(M, mlp[((size_t)p * NSLOT + c) * 2]);
  float L = 0.f, O = 0.f;
#pragma unroll 8
  for (int c = 0; c < NSLOT; ++c) {
    const float mi = mlp[((size_t)p * NSLOT + c) * 2];
    const float w = __expf(mi - M);
    L += w * mlp[((size_t)p * NSLOT + c) * 2 + 1];
    O += w * opart[((size_t)p * NSLOT + c) * HD + d];
  }
  ow[(size_t)p * HD + d] = O / L;
}

// ---------------- sum GEMM partials ----------------
__global__ __launch_bounds__(256)
void sum_partials(const float* __restrict__ part, float* __restrict__ out,
                  const int total4, const int nseg, const int stride) {
  const int i = blockIdx.x * 256 + threadIdx.x;
  if (i >= total4) return;
  float4 s = make_float4(0.f, 0.f, 0.f, 0.f);
  for (int g = 0; g < nseg; ++g) {
    const float4 v = *(const float4*)(part + (size_t)g * stride + (size_t)i * 4);
    s.x += v.x; s.y += v.y; s.z += v.z; s.w += v.w;
  }
  *(float4*)(out + (size_t)i * 4) = s;
}

extern "C" void kernel_launch(void* const* d_in, const int* in_sizes, int n_in,
                              void* d_out, int out_size, void* d_ws, size_t ws_size,
                              hipStream_t stream) {
  const float* x    = (const float*)d_in[0];
  const float* ck   = (const float*)d_in[1];
  const float* cv   = (const float*)d_in[2];
  const float* wqkv = (const float*)d_in[3];
  const float* wo   = (const float*)d_in[4];
  const int*   ctx  = (const int*)d_in[5];

  float* ws    = (float*)d_ws;
  float* pqkv  = ws;                                        // 8*32*6144
  float* qw    = pqkv + (size_t)NSEG * BATCH * QKVN;        // 32*4096
  float* kn    = qw + (size_t)BATCH * DIM;                  // 32*1024
  float* vn    = kn + (size_t)BATCH * NKV * HD;             // 32*1024
  float* opart = vn + (size_t)BATCH * NKV * HD;             // 1024*16*128
  float* mlp   = opart + (size_t)1024 * NSLOT * HD;         // 1024*16*2
  float* ow    = mlp + (size_t)1024 * NSLOT * 2;            // 32*4096
  float* pout  = pqkv;                                      // reuse (dead after qkv_combine)

  gemm_partial<<<dim3(QKVN / GN, NSEG), 256, 0, stream>>>(x, wqkv, pqkv, QKVN);
  qkv_combine<<<dim3(BATCH * QKVN / 2 / 256), 256, 0, stream>>>(pqkv, ctx, qw, kn, vn);
  attn_fd<<<dim3(BATCH * NCHB), 256, 0, stream>>>(qw, kn, vn, ck, cv, ctx, opart, mlp);
  attn_combine<<<dim3(BATCH * NHEAD), HD, 0, stream>>>(opart, mlp, ow);
  gemm_partial<<<dim3(DIM / GN, NSEG), 256, 0, stream>>>(ow, wo, pout, DIM);
  sum_partials<<<dim3((BATCH * DIM / 4 + 255) / 256), 256, 0, stream>>>(
      pout, (float*)d_out, BATCH * DIM / 4, NSEG, BATCH * DIM);
}